// Round 8
// baseline (387.426 us; speedup 1.0000x reference)
//
#include <hip/hip_runtime.h>
#include <cstdint>
#include <cstddef>

#define N_GENES  16384
#define N_LATENT 4096
#define D_K      64
#define N_CELLS  1024

#define NOISE_PARTITIONABLE 1

typedef __attribute__((ext_vector_type(8))) short bf16x8;
typedef __attribute__((ext_vector_type(4))) float f32x4;

// ---------------- Threefry-2x32-20, key = (0, 42) ----------------
__device__ __forceinline__ uint32_t rotl32(uint32_t x, int r) {
  return __builtin_amdgcn_alignbit(x, x, 32 - r);
}

__device__ __forceinline__ void threefry2x32(uint32_t c0, uint32_t c1,
                                             uint32_t& o0, uint32_t& o1) {
  const uint32_t ks0 = 0u, ks1 = 42u, ks2 = 0u ^ 42u ^ 0x1BD11BDAu;
  uint32_t x0 = c0 + ks0;
  uint32_t x1 = c1 + ks1;
#define TFR(r) { x0 += x1; x1 = rotl32(x1, r); x1 ^= x0; }
  TFR(13) TFR(15) TFR(26) TFR(6)
  x0 += ks1; x1 += ks2 + 1u;
  TFR(17) TFR(29) TFR(16) TFR(24)
  x0 += ks2; x1 += ks0 + 2u;
  TFR(13) TFR(15) TFR(26) TFR(6)
  x0 += ks0; x1 += ks1 + 3u;
  TFR(17) TFR(29) TFR(16) TFR(24)
  x0 += ks1; x1 += ks2 + 4u;
  TFR(13) TFR(15) TFR(26) TFR(6)
  x0 += ks2; x1 += ks0 + 5u;
#undef TFR
  o0 = x0; o1 = x1;
}

__device__ __forceinline__ uint32_t rand_bits(uint32_t m) {
#if NOISE_PARTITIONABLE
  uint32_t b0, b1;
  threefry2x32(0u, m, b0, b1);
  return b0 ^ b1;
#else
  const uint32_t h = 1u << 25;
  uint32_t b0, b1;
  if (m < h) { threefry2x32(m, m + h, b0, b1); return b0; }
  else       { threefry2x32(m - h, m, b0, b1); return b1; }
#endif
}

// fast ln(x): v_log_f32 (log2, ~1 ulp) * ln2
__device__ __forceinline__ float fastlog(float x) {
  float r;
  asm("v_log_f32 %0, %1" : "=v"(r) : "v"(x));
  return r * 0.69314718055994531f;
}

__device__ __forceinline__ float gumbel_noise(uint32_t m) {
  uint32_t bits = rand_bits(m);
  float f = __uint_as_float((bits >> 9) | 0x3f800000u) - 1.0f;
  float u = f + 1.17549435e-38f;
  float t = -fastlog(u);
  return -fastlog(t);
}

__device__ __forceinline__ ushort f2bf(float x) {
  uint32_t u = __float_as_uint(x);
  uint32_t r = (u + 0x7FFFu + ((u >> 16) & 1u)) >> 16;
  return (ushort)r;
}

__device__ __forceinline__ float bf2f(uint32_t us) {
  return __uint_as_float(us << 16);
}

// packed f32x2 -> bf16x2 (RNE), one instruction
__device__ __forceinline__ uint32_t cvtpk_bf16(float lo, float hi) {
  uint32_t r;
  asm("v_cvt_pk_bf16_f32 %0, %1, %2" : "=v"(r) : "v"(lo), "v"(hi));
  return r;
}

// swizzled LDS ushort index for a [64][64] bf16 tile (k1), XOR on 16B granules
__device__ __forceinline__ int swz(int row, int kcol) {
  return row * 64 + (((kcol >> 3) ^ (row & 7)) << 3) + (kcol & 7);
}

// ------- kernel 1: Pexp = bf16(exp(QK^T/8 + gumbel)), + row partial sums -------
__global__ __launch_bounds__(256) void k_logexp(const float* __restrict__ Q,
                                                const float* __restrict__ Kk,
                                                ushort* __restrict__ Pe,
                                                float* __restrict__ Sp) {
  // exactly 32768 B of LDS -> 5 blocks/CU (20 waves)
  __shared__ ushort Qh[64 * 64], Ql[64 * 64], Kh[64 * 64], Kl[64 * 64];
  float (*part)[2] = (float(*)[2])Ql;   // aliased after MFMA section
  const int t = threadIdx.x;
  const int bm = blockIdx.x, bn = blockIdx.y;
  const float4* Q4 = (const float4*)(Q + ((size_t)bm << 12));
  const float4* K4 = (const float4*)(Kk + ((size_t)bn << 12));
#pragma unroll
  for (int i = 0; i < 4; ++i) {
    int idx = t + (i << 8);
    int r = idx >> 4;
    int k0 = (idx & 15) << 2;
    int sidx = swz(r, k0);
    float4 a = Q4[idx];
    a.x *= 0.125f; a.y *= 0.125f; a.z *= 0.125f; a.w *= 0.125f;
    {
      uint32_t h01 = cvtpk_bf16(a.x, a.y), h23 = cvtpk_bf16(a.z, a.w);
      float lx = a.x - __uint_as_float(h01 << 16);
      float ly = a.y - __uint_as_float(h01 & 0xffff0000u);
      float lz = a.z - __uint_as_float(h23 << 16);
      float lw = a.w - __uint_as_float(h23 & 0xffff0000u);
      uint32_t l01 = cvtpk_bf16(lx, ly), l23 = cvtpk_bf16(lz, lw);
      *(uint2*)&Qh[sidx] = make_uint2(h01, h23);
      *(uint2*)&Ql[sidx] = make_uint2(l01, l23);
    }
    float4 b = K4[idx];
    {
      uint32_t h01 = cvtpk_bf16(b.x, b.y), h23 = cvtpk_bf16(b.z, b.w);
      float lx = b.x - __uint_as_float(h01 << 16);
      float ly = b.y - __uint_as_float(h01 & 0xffff0000u);
      float lz = b.z - __uint_as_float(h23 << 16);
      float lw = b.w - __uint_as_float(h23 & 0xffff0000u);
      uint32_t l01 = cvtpk_bf16(lx, ly), l23 = cvtpk_bf16(lz, lw);
      *(uint2*)&Kh[sidx] = make_uint2(h01, h23);
      *(uint2*)&Kl[sidx] = make_uint2(l01, l23);
    }
  }
  __syncthreads();

  const int l = t & 63, w = t >> 6;
  const int wm = (w >> 1) << 5, wn = (w & 1) << 5;  // 32x32 per wave
  const int fr = l & 15;
  const int seg = l >> 4;
  const int koff = seg << 3;
  f32x4 acc[2][2] = {};
#pragma unroll
  for (int kseg = 0; kseg < 2; ++kseg) {
    bf16x8 ah[2], al[2], bh[2], bl[2];
    const int kc = kseg * 32 + koff;
#pragma unroll
    for (int m = 0; m < 2; ++m) {
      int row = wm + m * 16 + fr;
      int sidx = swz(row, kc);
      ah[m] = *(const bf16x8*)&Qh[sidx];
      al[m] = *(const bf16x8*)&Ql[sidx];
    }
#pragma unroll
    for (int n = 0; n < 2; ++n) {
      int row = wn + n * 16 + fr;
      int sidx = swz(row, kc);
      bh[n] = *(const bf16x8*)&Kh[sidx];
      bl[n] = *(const bf16x8*)&Kl[sidx];
    }
#pragma unroll
    for (int m = 0; m < 2; ++m)
#pragma unroll
      for (int n = 0; n < 2; ++n) {
        acc[m][n] = __builtin_amdgcn_mfma_f32_16x16x32_bf16(
            ah[m], bh[n], acc[m][n], 0, 0, 0);
        acc[m][n] = __builtin_amdgcn_mfma_f32_16x16x32_bf16(
            ah[m], bl[n], acc[m][n], 0, 0, 0);
        acc[m][n] = __builtin_amdgcn_mfma_f32_16x16x32_bf16(
            al[m], bh[n], acc[m][n], 0, 0, 0);
      }
  }
  // all Ql reads done before part (aliased into Ql) is written
  __syncthreads();

  const float LOG2E = 1.44269504088896340f;
  const float NLN2 = -0.69314718055994531f;
  const int gr0 = (bm << 6) + wm + (seg << 2);
  const int gc0 = (bn << 6) + wn + fr;
  float sloc[2][4] = {};
#pragma unroll
  for (int m = 0; m < 2; ++m)
#pragma unroll
    for (int n = 0; n < 2; ++n) {
      int col = gc0 + n * 16;
      uint32_t mbase = (uint32_t)(gr0 + m * 16) * 4096u + (uint32_t)col;
      float e[4];
#pragma unroll
      for (int j = 0; j < 4; ++j) {
        uint32_t bits = rand_bits(mbase + (uint32_t)j * 4096u);
        float f = __uint_as_float((bits >> 9) | 0x3f800000u) - 1.0f;
        float u = f + 1.17549435e-38f;
        float lgu;
        asm("v_log_f32 %0, %1" : "=v"(lgu) : "v"(u));
        float tq = lgu * NLN2;                    // -ln(u) > 0
        float lgt;
        asm("v_log_f32 %0, %1" : "=v"(lgt) : "v"(tq));
        float ee;
        asm("v_exp_f32 %0, %1" : "=v"(ee)
            : "v"(fmaf(acc[m][n][j], LOG2E, -lgt)));  // exp(s)/(-ln u)
        e[j] = ee;
        sloc[m][j] += ee;
      }
      uint32_t p01 = cvtpk_bf16(e[0], e[1]);
      uint32_t p23 = cvtpk_bf16(e[2], e[3]);
      size_t base = (size_t)(gr0 + m * 16) * 4096 + col;
      Pe[base] = (ushort)p01;
      Pe[base + 4096] = (ushort)(p01 >> 16);
      Pe[base + 2 * 4096] = (ushort)p23;
      Pe[base + 3 * 4096] = (ushort)(p23 >> 16);
    }
#pragma unroll
  for (int m = 0; m < 2; ++m)
#pragma unroll
    for (int j = 0; j < 4; ++j) {
      float s = sloc[m][j];
      s += __shfl_xor(s, 1, 64); s += __shfl_xor(s, 2, 64);
      s += __shfl_xor(s, 4, 64); s += __shfl_xor(s, 8, 64);
      if (fr == 0) part[wm + m * 16 + (seg << 2) + j][wn >> 5] = s;
    }
  __syncthreads();
  if (t < 64)
    Sp[((size_t)(bm << 6) + t) * 64 + bn] = part[t][0] + part[t][1];
}

// ------- kernel 1b: inv[r] = 1 / sum_i Sp[r][i] -------
__global__ __launch_bounds__(256) void k_rowinv(const float* __restrict__ Sp,
                                                float* __restrict__ inv) {
  int r = blockIdx.x * 256 + threadIdx.x;
  const float4* s4 = (const float4*)(Sp + (size_t)r * 64);
  float s = 0.f;
#pragma unroll
  for (int i = 0; i < 16; ++i) {
    float4 v = s4[i];
    s += (v.x + v.y) + (v.z + v.w);
  }
  inv[r] = 1.0f / s;
}

// ------- kernel 2b: VT[n][k] = bf16(V[k][n]) -------
__global__ __launch_bounds__(256) void k_vt(const float* __restrict__ V,
                                            ushort* __restrict__ VT) {
  __shared__ ushort tile[64][68];
  const int t = threadIdx.x;
  const int k0 = blockIdx.x << 6, n0 = blockIdx.y << 6;
#pragma unroll
  for (int i = 0; i < 16; ++i) {
    int idx = t + (i << 8);
    int kr = idx >> 6;
    int c = idx & 63;
    tile[c][kr] = f2bf(V[(size_t)(k0 + kr) * 1024 + n0 + c]);
  }
  __syncthreads();
#pragma unroll
  for (int i = 0; i < 8; ++i) {
    int idx = t + (i << 8);
    int n = idx >> 5, kp = idx & 31;
    ushort2 o;
    o.x = tile[n][2 * kp];
    o.y = tile[n][2 * kp + 1];
    ((ushort2*)&VT[(size_t)(n0 + n) * 4096 + k0])[kp] = o;
  }
}

// ------- kernel 3: O = inv ⊙ (Pexp @ VT^T) + fused P-write, 128² 2-blk/CU -------
__device__ __forceinline__ void llds16(void* lds, const void* g) {
  __builtin_amdgcn_global_load_lds(
      (const __attribute__((address_space(1))) uint32_t*)g,
      (__attribute__((address_space(3))) uint32_t*)lds, 16, 0, 0);
}

// stage a 128x64 bf16 tile: linear LDS dest, inverse-swizzled global source
__device__ __forceinline__ void stage128(ushort* ldsS, const ushort* gS,
                                         int t) {
#pragma unroll
  for (int i = 0; i < 4; ++i) {
    int cid = (i << 8) + t;            // 0..1023 16B-chunks
    int row = cid >> 3, g = cid & 7;
    int gs = g ^ (row & 7);
    llds16(ldsS + (size_t)cid * 8, gS + (size_t)row * 4096 + gs * 8);
  }
}

__global__ __launch_bounds__(256, 2) void k_pv6(const ushort* __restrict__ Pe,
                                                const ushort* __restrict__ VT,
                                                const float* __restrict__ inv,
                                                float* __restrict__ P,
                                                float* __restrict__ O) {
  __shared__ ushort lds[2][2][128 * 64];   // [slot][A/B] 64 KB -> 2 blocks/CU
  const int t = threadIdx.x;
  // XCD swizzle (pv2-proven): 8 n-siblings sharing an A-panel -> same XCD
  const int b = blockIdx.x;            // 0..1023
  const int Lb = (b & 7) * 128 + (b >> 3);
  const int by = Lb >> 3, bx = Lb & 7;
  const int base_m = by << 7, base_n = bx << 7;
  const int l = t & 63, w = t >> 6;    // 4 waves
  const int wm = (w >> 1) << 6, wn = (w & 1) << 6;
  const int fr = l & 15, seg = l >> 4;

  const ushort* gA = Pe + (size_t)base_m * 4096;
  const ushort* gB = VT + (size_t)base_n * 4096;

  // fused P-write: this block writes A-panel rows [bx*16, bx*16+16)
  const int pr_loc = (bx << 4) + (t >> 4);     // 16 rows
  const int pcg = t & 15;                      // 4-float col group
  const int pw_ldsoff = pr_loc * 64 + (((pcg >> 1) ^ (pr_loc & 7)) << 3) +
                        (pcg & 1) * 4;         // ushort idx of 4 bf16
  const int pw_row = base_m + pr_loc;
  const float iv_pw = inv[pw_row];
  float* Pdst = P + (size_t)pw_row * 4096 + pcg * 4;

  f32x4 acc[4][4] = {};

  // prologue: K-tile 0 -> slot 0, fully drained
  stage128(lds[0][0], gA, t);
  stage128(lds[0][1], gB, t);
  asm volatile("s_waitcnt vmcnt(0)" ::: "memory");
  __builtin_amdgcn_s_barrier();

  for (int it = 0; it < 64; ++it) {
    const int slot = it & 1;
    // top gate: queue = [loads_it(8), store_{it-1}(1)] -> vmcnt(1) drains
    // exactly the 8 loads for tile it; P-stores stay fire-and-forget.
    if (it > 0) {
      asm volatile("s_waitcnt vmcnt(1)" ::: "memory");
      __builtin_amdgcn_s_barrier();
    }
    const ushort* A = lds[slot][0];
    const ushort* B = lds[slot][1];
    if (it < 63) {
      stage128(lds[slot ^ 1][0], gA + (it + 1) * 64, t);
      stage128(lds[slot ^ 1][1], gB + (it + 1) * 64, t);
    }
    bf16x8 a[4][2], bb[4][2];
#pragma unroll
    for (int mi = 0; mi < 4; ++mi)
#pragma unroll
      for (int kk = 0; kk < 2; ++kk) {
        int row = wm + mi * 16 + fr;
        a[mi][kk] = *(const bf16x8*)
            &A[row * 64 + ((((kk << 2) + seg) ^ (row & 7)) << 3)];
      }
#pragma unroll
    for (int ni = 0; ni < 4; ++ni)
#pragma unroll
      for (int kk = 0; kk < 2; ++kk) {
        int row = wn + ni * 16 + fr;
        bb[ni][kk] = *(const bf16x8*)
            &B[row * 64 + ((((kk << 2) + seg) ^ (row & 7)) << 3)];
      }
    __builtin_amdgcn_s_setprio(1);
#pragma unroll
    for (int kk = 0; kk < 2; ++kk)
#pragma unroll
      for (int mi = 0; mi < 4; ++mi)
#pragma unroll
        for (int ni = 0; ni < 4; ++ni)
          acc[mi][ni] = __builtin_amdgcn_mfma_f32_16x16x32_bf16(
              a[mi][kk], bb[ni][kk], acc[mi][ni], 0, 0, 0);
    __builtin_amdgcn_s_setprio(0);
    // fused P-write for K-tile it (4 bf16 -> float4)
    {
      uint2 pw = *(const uint2*)&A[pw_ldsoff];
      float4 o;
      o.x = bf2f(pw.x & 0xFFFFu) * iv_pw;
      o.y = bf2f(pw.x >> 16) * iv_pw;
      o.z = bf2f(pw.y & 0xFFFFu) * iv_pw;
      o.w = bf2f(pw.y >> 16) * iv_pw;
      *(float4*)(Pdst + (size_t)it * 64) = o;
    }
    __builtin_amdgcn_s_barrier();
  }

  const int orow0 = base_m + wm + seg * 4;
  const int ocol0 = base_n + wn + fr;
#pragma unroll
  for (int mi = 0; mi < 4; ++mi) {
    int row_ = orow0 + mi * 16;
#pragma unroll
    for (int j = 0; j < 4; ++j) {
      float iv = inv[row_ + j];
#pragma unroll
      for (int ni = 0; ni < 4; ++ni)
        O[(size_t)(row_ + j) * 1024 + ocol0 + ni * 16] =
            acc[mi][ni][j] * iv;
    }
  }
}

// ================= fallback fp32 path (tiny-ws safety net) =================
__global__ __launch_bounds__(256) void k_logits_raw(const float* __restrict__ Q,
                                                    const float* __restrict__ Kk,
                                                    float* __restrict__ L) {
  __shared__ float Qt[64][68];
  __shared__ float Kt[64][68];
  const int t = threadIdx.x;
  const int bm = blockIdx.x, bn = blockIdx.y;
  const float4* Q4 = (const float4*)(Q + ((size_t)bm << 12));
  const float4* K4 = (const float4*)(Kk + ((size_t)bn << 12));
#pragma unroll
  for (int i = 0; i < 4; ++i) {
    int idx = t + (i << 8);
    int r = idx >> 4;
    int k0 = (idx & 15) << 2;
    float4 a = Q4[idx];
    Qt[k0 + 0][r] = a.x; Qt[k0 + 1][r] = a.y;
    Qt[k0 + 2][r] = a.z; Qt[k0 + 3][r] = a.w;
    float4 b = K4[idx];
    Kt[k0 + 0][r] = b.x; Kt[k0 + 1][r] = b.y;
    Kt[k0 + 2][r] = b.z; Kt[k0 + 3][r] = b.w;
  }
  __syncthreads();
  const int r0 = (t >> 4) << 2;
  const int c0 = (t & 15) << 2;
  float acc[4][4] = {};
#pragma unroll 8
  for (int k = 0; k < 64; ++k) {
    float a[4], b[4];
    *(float4*)a = *(const float4*)&Qt[k][r0];
    *(float4*)b = *(const float4*)&Kt[k][c0];
#pragma unroll
    for (int i = 0; i < 4; ++i)
#pragma unroll
      for (int j = 0; j < 4; ++j)
        acc[i][j] = fmaf(a[i], b[j], acc[i][j]);
  }
  const int gr = (bm << 6) + r0;
  const int gc = (bn << 6) + c0;
#pragma unroll
  for (int i = 0; i < 4; ++i) {
    uint32_t mb = (uint32_t)(gr + i) * 4096u + (uint32_t)gc;
    float4 o;
    o.x = acc[i][0] * 0.125f + gumbel_noise(mb + 0u);
    o.y = acc[i][1] * 0.125f + gumbel_noise(mb + 1u);
    o.z = acc[i][2] * 0.125f + gumbel_noise(mb + 2u);
    o.w = acc[i][3] * 0.125f + gumbel_noise(mb + 3u);
    *(float4*)&L[(size_t)(gr + i) * 4096 + gc] = o;
  }
}

__global__ __launch_bounds__(256) void k_softmax(float* __restrict__ P) {
  const int row = blockIdx.x;
  float* Lr = P + ((size_t)row << 12);
  const int t = threadIdx.x;
  float4 v[4];
#pragma unroll
  for (int i = 0; i < 4; ++i) v[i] = ((const float4*)Lr)[t + (i << 8)];
  float mx = -3.402823466e38f;
#pragma unroll
  for (int i = 0; i < 4; ++i)
    mx = fmaxf(mx, fmaxf(fmaxf(v[i].x, v[i].y), fmaxf(v[i].z, v[i].w)));
#pragma unroll
  for (int o = 1; o < 64; o <<= 1) mx = fmaxf(mx, __shfl_xor(mx, o, 64));
  __shared__ float redm[4];
  __shared__ float reds[4];
  const int lane = t & 63, w = t >> 6;
  if (lane == 0) redm[w] = mx;
  __syncthreads();
  mx = fmaxf(fmaxf(redm[0], redm[1]), fmaxf(redm[2], redm[3]));
  float s = 0.f;
#pragma unroll
  for (int i = 0; i < 4; ++i) {
    v[i].x = expf(v[i].x - mx); v[i].y = expf(v[i].y - mx);
    v[i].z = expf(v[i].z - mx); v[i].w = expf(v[i].w - mx);
    s += (v[i].x + v[i].y) + (v[i].z + v[i].w);
  }
#pragma unroll
  for (int o = 1; o < 64; o <<= 1) s += __shfl_xor(s, o, 64);
  if (lane == 0) reds[w] = s;
  __syncthreads();
  const float inv = 1.0f / (((reds[0] + reds[1]) + (reds[2] + reds[3])));
#pragma unroll
  for (int i = 0; i < 4; ++i) {
    v[i].x *= inv; v[i].y *= inv; v[i].z *= inv; v[i].w *= inv;
    ((float4*)Lr)[t + (i << 8)] = v[i];
  }
}

__global__ __launch_bounds__(256) void k_pv(const float* __restrict__ P,
                                            const float* __restrict__ V,
                                            float* __restrict__ O) {
  __shared__ float Pt[32][132];
  __shared__ float Vs[32][132];
  const int t = threadIdx.x;
  const int base_m = blockIdx.x << 7;
  const int base_n = blockIdx.y << 7;
  const int tr = (t >> 4) << 2;
  const int tc = (t & 15) << 2;
  float acc[2][2][4][4] = {};
  for (int k0 = 0; k0 < N_LATENT; k0 += 32) {
#pragma unroll
    for (int i = 0; i < 4; ++i) {
      int idx = t + (i << 8);
      int m = idx >> 3;
      int kk = (idx & 7) << 2;
      float4 a = *(const float4*)&P[(size_t)(base_m + m) * 4096 + (k0 + kk)];
      Pt[kk + 0][m] = a.x; Pt[kk + 1][m] = a.y;
      Pt[kk + 2][m] = a.z; Pt[kk + 3][m] = a.w;
      int kv = idx >> 5;
      int n4 = (idx & 31) << 2;
      *(float4*)&Vs[kv][n4] =
          *(const float4*)&V[(size_t)(k0 + kv) * 1024 + base_n + n4];
    }
    __syncthreads();
#pragma unroll 4
    for (int k = 0; k < 32; ++k) {
      float a[2][4], b[2][4];
      *(float4*)a[0] = *(const float4*)&Pt[k][tr];
      *(float4*)a[1] = *(const float4*)&Pt[k][tr + 64];
      *(float4*)b[0] = *(const float4*)&Vs[k][tc];
      *(float4*)b[1] = *(const float4*)&Vs[k][tc + 64];
#pragma unroll
      for (int ih = 0; ih < 2; ++ih)
#pragma unroll
        for (int jh = 0; jh < 2; ++jh)
#pragma unroll
          for (int i = 0; i < 4; ++i)
#pragma unroll
            for (int j = 0; j < 4; ++j)
              acc[ih][jh][i][j] =
                  fmaf(a[ih][i], b[jh][j], acc[ih][jh][i][j]);
    }
    __syncthreads();
  }
#pragma unroll
  for (int ih = 0; ih < 2; ++ih)
#pragma unroll
    for (int i = 0; i < 4; ++i) {
      int row = base_m + (ih << 6) + tr + i;
#pragma unroll
      for (int jh = 0; jh < 2; ++jh) {
        float4 o;
        o.x = acc[ih][jh][i][0]; o.y = acc[ih][jh][i][1];
        o.z = acc[ih][jh][i][2]; o.w = acc[ih][jh][i][3];
        *(float4*)&O[(size_t)row * 1024 + base_n + (jh << 6) + tc] = o;
      }
    }
}

extern "C" void kernel_launch(void* const* d_in, const int* in_sizes, int n_in,
                              void* d_out, int out_size, void* d_ws, size_t ws_size,
                              hipStream_t stream) {
  const float* Q = (const float*)d_in[0];
  const float* K = (const float*)d_in[1];
  const float* V = (const float*)d_in[2];
  float* O = (float*)d_out;                      // [16384 x 1024]
  float* P = O + (size_t)N_GENES * N_CELLS;      // [16384 x 4096] fp32 p_attn

  const size_t pe_bytes = (size_t)N_GENES * N_LATENT * 2;   // 134.2 MB
  const size_t vt_bytes = (size_t)N_CELLS * N_LATENT * 2;   // 8.4 MB
  const size_t inv_bytes = (size_t)N_GENES * 4;             // 64 KB
  const bool fast = ws_size >= pe_bytes + vt_bytes + inv_bytes;

  if (fast) {
    ushort* Pe = (ushort*)d_ws;
    ushort* VT = (ushort*)((char*)d_ws + pe_bytes);
    float* inv = (float*)((char*)d_ws + pe_bytes + vt_bytes);
    float* Sp = P;  // 16384x64 fp32 scratch in P-region; overwritten by k_pv6

    k_logexp<<<dim3(N_GENES / 64, N_LATENT / 64), 256, 0, stream>>>(Q, K, Pe, Sp);
    k_rowinv<<<N_GENES / 256, 256, 0, stream>>>(Sp, inv);
    k_vt<<<dim3(N_LATENT / 64, N_CELLS / 64), 256, 0, stream>>>(V, VT);
    k_pv6<<<(N_GENES / 128) * (N_CELLS / 128), 256, 0, stream>>>(Pe, VT, inv, P, O);
  } else {
    k_logits_raw<<<dim3(N_GENES / 64, N_LATENT / 64), 256, 0, stream>>>(Q, K, P);
    k_softmax<<<N_GENES, 256, 0, stream>>>(P);
    k_pv<<<dim3(N_GENES / 128, N_CELLS / 128), 256, 0, stream>>>(P, V, O);
  }
}

// Round 9
// 329.058 us; speedup vs baseline: 1.1774x; 1.1774x over previous
//
#include <hip/hip_runtime.h>
#include <cstdint>
#include <cstddef>

#define N_GENES  16384
#define N_LATENT 4096
#define D_K      64
#define N_CELLS  1024

#define NOISE_PARTITIONABLE 1

typedef __attribute__((ext_vector_type(8))) short bf16x8;
typedef __attribute__((ext_vector_type(4))) float f32x4;

// ---------------- Threefry-2x32-20, key = (0, 42) ----------------
__device__ __forceinline__ uint32_t rotl32(uint32_t x, int r) {
  return __builtin_amdgcn_alignbit(x, x, 32 - r);
}

__device__ __forceinline__ void threefry2x32(uint32_t c0, uint32_t c1,
                                             uint32_t& o0, uint32_t& o1) {
  const uint32_t ks0 = 0u, ks1 = 42u, ks2 = 0u ^ 42u ^ 0x1BD11BDAu;
  uint32_t x0 = c0 + ks0;
  uint32_t x1 = c1 + ks1;
#define TFR(r) { x0 += x1; x1 = rotl32(x1, r); x1 ^= x0; }
  TFR(13) TFR(15) TFR(26) TFR(6)
  x0 += ks1; x1 += ks2 + 1u;
  TFR(17) TFR(29) TFR(16) TFR(24)
  x0 += ks2; x1 += ks0 + 2u;
  TFR(13) TFR(15) TFR(26) TFR(6)
  x0 += ks0; x1 += ks1 + 3u;
  TFR(17) TFR(29) TFR(16) TFR(24)
  x0 += ks1; x1 += ks2 + 4u;
  TFR(13) TFR(15) TFR(26) TFR(6)
  x0 += ks2; x1 += ks0 + 5u;
#undef TFR
  o0 = x0; o1 = x1;
}

__device__ __forceinline__ uint32_t rand_bits(uint32_t m) {
#if NOISE_PARTITIONABLE
  uint32_t b0, b1;
  threefry2x32(0u, m, b0, b1);
  return b0 ^ b1;
#else
  const uint32_t h = 1u << 25;
  uint32_t b0, b1;
  if (m < h) { threefry2x32(m, m + h, b0, b1); return b0; }
  else       { threefry2x32(m - h, m, b0, b1); return b1; }
#endif
}

// fast ln(x): v_log_f32 (log2, ~1 ulp) * ln2
__device__ __forceinline__ float fastlog(float x) {
  float r;
  asm("v_log_f32 %0, %1" : "=v"(r) : "v"(x));
  return r * 0.69314718055994531f;
}

__device__ __forceinline__ float gumbel_noise(uint32_t m) {
  uint32_t bits = rand_bits(m);
  float f = __uint_as_float((bits >> 9) | 0x3f800000u) - 1.0f;
  float u = f + 1.17549435e-38f;
  float t = -fastlog(u);
  return -fastlog(t);
}

__device__ __forceinline__ ushort f2bf(float x) {
  uint32_t u = __float_as_uint(x);
  uint32_t r = (u + 0x7FFFu + ((u >> 16) & 1u)) >> 16;
  return (ushort)r;
}

__device__ __forceinline__ float bf2f(uint32_t us) {
  return __uint_as_float(us << 16);
}

// packed f32x2 -> bf16x2 (RNE), one instruction
__device__ __forceinline__ uint32_t cvtpk_bf16(float lo, float hi) {
  uint32_t r;
  asm("v_cvt_pk_bf16_f32 %0, %1, %2" : "=v"(r) : "v"(lo), "v"(hi));
  return r;
}

// swizzled LDS ushort index for a [64][64] bf16 tile (k1), XOR on 16B granules
__device__ __forceinline__ int swz(int row, int kcol) {
  return row * 64 + (((kcol >> 3) ^ (row & 7)) << 3) + (kcol & 7);
}

// ------- kernel 1: Pexp = bf16(exp(QK^T/8 + gumbel)), + row partial sums -------
// Swapped-operand MFMA: acc[m][n] = S^T fragment, so each lane holds 4
// CONSECUTIVE k-cols of ONE q-row -> single uint2 Pe store, row-local sums.
__global__ __launch_bounds__(256) void k_logexp(const float* __restrict__ Q,
                                                const float* __restrict__ Kk,
                                                ushort* __restrict__ Pe,
                                                float* __restrict__ Sp) {
  // exactly 32768 B of LDS -> 5 blocks/CU
  __shared__ ushort Qh[64 * 64], Ql[64 * 64], Kh[64 * 64], Kl[64 * 64];
  float (*part)[2] = (float(*)[2])Ql;   // aliased after MFMA section
  const int t = threadIdx.x;
  const int bm = blockIdx.x, bn = blockIdx.y;
  const float4* Q4 = (const float4*)(Q + ((size_t)bm << 12));
  const float4* K4 = (const float4*)(Kk + ((size_t)bn << 12));
#pragma unroll
  for (int i = 0; i < 4; ++i) {
    int idx = t + (i << 8);
    int r = idx >> 4;
    int k0 = (idx & 15) << 2;
    int sidx = swz(r, k0);
    float4 a = Q4[idx];
    a.x *= 0.125f; a.y *= 0.125f; a.z *= 0.125f; a.w *= 0.125f;
    {
      uint32_t h01 = cvtpk_bf16(a.x, a.y), h23 = cvtpk_bf16(a.z, a.w);
      float lx = a.x - __uint_as_float(h01 << 16);
      float ly = a.y - __uint_as_float(h01 & 0xffff0000u);
      float lz = a.z - __uint_as_float(h23 << 16);
      float lw = a.w - __uint_as_float(h23 & 0xffff0000u);
      uint32_t l01 = cvtpk_bf16(lx, ly), l23 = cvtpk_bf16(lz, lw);
      *(uint2*)&Qh[sidx] = make_uint2(h01, h23);
      *(uint2*)&Ql[sidx] = make_uint2(l01, l23);
    }
    float4 b = K4[idx];
    {
      uint32_t h01 = cvtpk_bf16(b.x, b.y), h23 = cvtpk_bf16(b.z, b.w);
      float lx = b.x - __uint_as_float(h01 << 16);
      float ly = b.y - __uint_as_float(h01 & 0xffff0000u);
      float lz = b.z - __uint_as_float(h23 << 16);
      float lw = b.w - __uint_as_float(h23 & 0xffff0000u);
      uint32_t l01 = cvtpk_bf16(lx, ly), l23 = cvtpk_bf16(lz, lw);
      *(uint2*)&Kh[sidx] = make_uint2(h01, h23);
      *(uint2*)&Kl[sidx] = make_uint2(l01, l23);
    }
  }
  __syncthreads();

  const int l = t & 63, w = t >> 6;
  const int wm = (w >> 1) << 5, wn = (w & 1) << 5;  // 32x32 per wave
  const int fr = l & 15;
  const int seg = l >> 4;
  const int koff = seg << 3;
  f32x4 acc[2][2] = {};
#pragma unroll
  for (int kseg = 0; kseg < 2; ++kseg) {
    bf16x8 ah[2], al[2], bh[2], bl[2];
    const int kc = kseg * 32 + koff;
#pragma unroll
    for (int m = 0; m < 2; ++m) {
      int row = wm + m * 16 + fr;
      int sidx = swz(row, kc);
      ah[m] = *(const bf16x8*)&Qh[sidx];
      al[m] = *(const bf16x8*)&Ql[sidx];
    }
#pragma unroll
    for (int n = 0; n < 2; ++n) {
      int row = wn + n * 16 + fr;
      int sidx = swz(row, kc);
      bh[n] = *(const bf16x8*)&Kh[sidx];
      bl[n] = *(const bf16x8*)&Kl[sidx];
    }
    // SWAPPED operands: D = K_tile x Q_tile -> S^T fragment layout
#pragma unroll
    for (int m = 0; m < 2; ++m)
#pragma unroll
      for (int n = 0; n < 2; ++n) {
        acc[m][n] = __builtin_amdgcn_mfma_f32_16x16x32_bf16(
            bh[n], ah[m], acc[m][n], 0, 0, 0);
        acc[m][n] = __builtin_amdgcn_mfma_f32_16x16x32_bf16(
            bl[n], ah[m], acc[m][n], 0, 0, 0);
        acc[m][n] = __builtin_amdgcn_mfma_f32_16x16x32_bf16(
            bh[n], al[m], acc[m][n], 0, 0, 0);
      }
  }
  // all Ql reads done before part (aliased into Ql) is written
  __syncthreads();

  const float LOG2E = 1.44269504088896340f;
  const float NLN2 = -0.69314718055994531f;
  float sloc[2] = {0.f, 0.f};
#pragma unroll
  for (int m = 0; m < 2; ++m) {
    const int q = (bm << 6) + wm + m * 16 + fr;         // q-row (lane-fixed)
#pragma unroll
    for (int n = 0; n < 2; ++n) {
      const int colb = (bn << 6) + wn + n * 16 + (seg << 2);
      uint32_t mb = (uint32_t)q * 4096u + (uint32_t)colb;
      float e[4];
#pragma unroll
      for (int j = 0; j < 4; ++j) {
        uint32_t bits = rand_bits(mb + (uint32_t)j);
        float f = __uint_as_float((bits >> 9) | 0x3f800000u) - 1.0f;
        float u = f + 1.17549435e-38f;
        float lgu;
        asm("v_log_f32 %0, %1" : "=v"(lgu) : "v"(u));
        float tq = lgu * NLN2;                    // -ln(u) > 0
        float lgt;
        asm("v_log_f32 %0, %1" : "=v"(lgt) : "v"(tq));
        float ee;
        asm("v_exp_f32 %0, %1" : "=v"(ee)
            : "v"(fmaf(acc[m][n][j], LOG2E, -lgt)));  // exp(s)/(-ln u)
        e[j] = ee;
      }
      sloc[m] += (e[0] + e[1]) + (e[2] + e[3]);
      uint32_t p01 = cvtpk_bf16(e[0], e[1]);
      uint32_t p23 = cvtpk_bf16(e[2], e[3]);
      *(uint2*)&Pe[(size_t)q * 4096 + colb] = make_uint2(p01, p23);
    }
  }
  // row-sum reduce: lanes fr, fr+16, fr+32, fr+48 share the same q-row
#pragma unroll
  for (int m = 0; m < 2; ++m) {
    float s = sloc[m];
    s += __shfl_xor(s, 16, 64);
    s += __shfl_xor(s, 32, 64);
    if (l < 16) part[wm + m * 16 + fr][wn >> 5] = s;
  }
  __syncthreads();
  if (t < 64)
    Sp[((size_t)(bm << 6) + t) * 64 + bn] = part[t][0] + part[t][1];
}

// ------- kernel 1b: inv[r] = 1 / sum_i Sp[r][i] -------
__global__ __launch_bounds__(256) void k_rowinv(const float* __restrict__ Sp,
                                                float* __restrict__ inv) {
  int r = blockIdx.x * 256 + threadIdx.x;
  const float4* s4 = (const float4*)(Sp + (size_t)r * 64);
  float s = 0.f;
#pragma unroll
  for (int i = 0; i < 16; ++i) {
    float4 v = s4[i];
    s += (v.x + v.y) + (v.z + v.w);
  }
  inv[r] = 1.0f / s;
}

// ------- kernel 2b: VT[n][k] = bf16(V[k][n]) -------
__global__ __launch_bounds__(256) void k_vt(const float* __restrict__ V,
                                            ushort* __restrict__ VT) {
  __shared__ ushort tile[64][68];
  const int t = threadIdx.x;
  const int k0 = blockIdx.x << 6, n0 = blockIdx.y << 6;
#pragma unroll
  for (int i = 0; i < 16; ++i) {
    int idx = t + (i << 8);
    int kr = idx >> 6;
    int c = idx & 63;
    tile[c][kr] = f2bf(V[(size_t)(k0 + kr) * 1024 + n0 + c]);
  }
  __syncthreads();
#pragma unroll
  for (int i = 0; i < 8; ++i) {
    int idx = t + (i << 8);
    int n = idx >> 5, kp = idx & 31;
    ushort2 o;
    o.x = tile[n][2 * kp];
    o.y = tile[n][2 * kp + 1];
    ((ushort2*)&VT[(size_t)(n0 + n) * 4096 + k0])[kp] = o;
  }
}

// ------- kernel 3: O = inv ⊙ (Pexp @ VT^T) + fused P-write, phase-pipelined -------
__device__ __forceinline__ void llds16(void* lds, const void* g) {
  __builtin_amdgcn_global_load_lds(
      (const __attribute__((address_space(1))) uint32_t*)g,
      (__attribute__((address_space(3))) uint32_t*)lds, 16, 0, 0);
}

// stage a full K-tile (256x64 bf16, A or B) -> 4 loads/thread
__device__ __forceinline__ void stage_full(ushort* ldsS, const ushort* gS,
                                           int t) {
#pragma unroll
  for (int i = 0; i < 4; ++i) {
    int cid = (i << 9) + t;            // 0..2047 16B-chunks
    int row = cid >> 3, g = cid & 7;
    int gs = g ^ (row & 7);
    llds16(ldsS + (size_t)cid * 8, gS + (size_t)row * 4096 + gs * 8);
  }
}

// stage a half K-tile (rows [rowoff, rowoff+128)) -> 2 loads/thread
__device__ __forceinline__ void stage_half(ushort* ldsS, const ushort* gS,
                                           int rowoff, int t) {
#pragma unroll
  for (int i = 0; i < 2; ++i) {
    int cid = (i << 9) + t;            // 0..1023
    int row = rowoff + (cid >> 3);
    int g = cid & 7;
    int gs = g ^ (row & 7);
    llds16(ldsS + ((size_t)row * 8 + g) * 8,
           gS + (size_t)row * 4096 + gs * 8);
  }
}

__global__ __launch_bounds__(512, 2) void k_pv5(const ushort* __restrict__ Pe,
                                                const ushort* __restrict__ VT,
                                                const float* __restrict__ inv,
                                                float* __restrict__ P,
                                                float* __restrict__ O) {
  __shared__ ushort lds[2][2][256 * 64];   // [slot][A/B] 128 KB
  const int t = threadIdx.x;
  // bijective XCD-aware swizzle: 4 n-blocks sharing an A-panel -> same XCD
  const int b = blockIdx.x;            // 0..255
  const int xcd = b & 7, idx = b >> 3; // 32 blocks per XCD
  const int by = xcd * 8 + (idx >> 2);
  const int bx = idx & 3;
  const int base_m = by << 8, base_n = bx << 8;
  const int l = t & 63, w = t >> 6;
  const int wm = w >> 2, wn = w & 3;   // 2 x 4 waves, 128x64 out each
  const int fr = l & 15, seg = l >> 4;

  const ushort* gA = Pe + (size_t)base_m * 4096;
  const ushort* gB = VT + (size_t)base_n * 4096;

  // fused P-write: this block writes A-panel rows [bx*64, bx*64+64)
  const int pr_loc = bx * 64 + (t >> 3);
  const int pw_g = t & 7;
  const int pw_off = pr_loc * 64 + ((pw_g ^ (pr_loc & 7)) << 3);  // ushort idx
  const int pw_row = base_m + pr_loc;
  const float iv_pw = inv[pw_row];
  float* Pdst = P + (size_t)pw_row * 4096 + pw_g * 8;

  f32x4 acc[8][4] = {};

  // prologue: K-tile 0 -> slot 0, fully drained
  stage_full(lds[0][0], gA, t);
  stage_full(lds[0][1], gB, t);
  asm volatile("s_waitcnt vmcnt(0)" ::: "memory");
  __builtin_amdgcn_s_barrier();

#define LDA_H(mh)                                                            \
  {                                                                          \
    _Pragma("unroll") for (int m = 0; m < 4; ++m)                            \
        _Pragma("unroll") for (int kk = 0; kk < 2; ++kk) {                   \
      int row = wm * 128 + (mh)*64 + m * 16 + fr;                            \
      a[m][kk] = *(const bf16x8*)&A[row * 64 +                               \
                                    ((((kk << 2) + seg) ^ (row & 7)) << 3)]; \
    }                                                                        \
  }
#define LDB_H(dst, nh)                                                       \
  {                                                                          \
    _Pragma("unroll") for (int n = 0; n < 2; ++n)                            \
        _Pragma("unroll") for (int kk = 0; kk < 2; ++kk) {                   \
      int row = wn * 64 + (nh)*32 + n * 16 + fr;                             \
      dst[n][kk] = *(const bf16x8*)&B[row * 64 +                             \
                                    ((((kk << 2) + seg) ^ (row & 7)) << 3)]; \
    }                                                                        \
  }
#define QUADM(mh, nh, bb)                                                    \
  {                                                                          \
    __builtin_amdgcn_s_setprio(1);                                           \
    _Pragma("unroll") for (int m = 0; m < 4; ++m)                            \
        _Pragma("unroll") for (int n = 0; n < 2; ++n)                        \
            _Pragma("unroll") for (int kk = 0; kk < 2; ++kk)                 \
        acc[(mh)*4 + m][(nh)*2 + n] = __builtin_amdgcn_mfma_f32_16x16x32_bf16( \
            a[m][kk], bb[n][kk], acc[(mh)*4 + m][(nh)*2 + n], 0, 0, 0);      \
    __builtin_amdgcn_s_setprio(0);                                           \
  }

  for (int it = 0; it < 64; ++it) {
    const int slot = it & 1;
    const ushort* A = lds[slot][0];
    const ushort* B = lds[slot][1];
    ushort* An = lds[slot ^ 1][0];
    ushort* Bn = lds[slot ^ 1][1];
    const ushort* gAn = gA + (it + 1) * 64;
    const ushort* gBn = gB + (it + 1) * 64;
    // gate at TOP: drains tile it's 8 loads (issued during iter it-1);
    // queue = [loads_it(8), stores_{it-1}(2)] -> vmcnt(2) never waits on
    // stores younger than ~1 iteration. (it==0 handled by prologue drain.)
    if (it > 0) {
      asm volatile("s_waitcnt vmcnt(2)" ::: "memory");
      __builtin_amdgcn_s_barrier();
    }
    bf16x8 a[4][2], b0[2][2], b1[2][2];
    // phase 0: lda0+ldb0 | stage A-half0(it+1) | barrier | 16 MFMA | barrier
    LDA_H(0) LDB_H(b0, 0)
    if (it < 63) stage_half(An, gAn, 0, t);
    __builtin_amdgcn_s_barrier();
    QUADM(0, 0, b0)
    __builtin_amdgcn_s_barrier();
    // phase 1
    LDB_H(b1, 1)
    if (it < 63) stage_half(An, gAn, 128, t);
    __builtin_amdgcn_s_barrier();
    QUADM(0, 1, b1)
    __builtin_amdgcn_s_barrier();
    // phase 2
    LDA_H(1)
    if (it < 63) stage_half(Bn, gBn, 0, t);
    __builtin_amdgcn_s_barrier();
    QUADM(1, 0, b0)
    __builtin_amdgcn_s_barrier();
    // phase 3
    if (it < 63) stage_half(Bn, gBn, 128, t);
    __builtin_amdgcn_s_barrier();
    QUADM(1, 1, b1)
    // fused P-write for K-tile it (reads slot cur; stores fire-and-forget)
    {
      bf16x8 pv_ = *(const bf16x8*)&A[pw_off];
      const uint32_t* pu = (const uint32_t*)&pv_;
      float4 o0, o1;
      uint32_t w0 = pu[0], w1 = pu[1], w2 = pu[2], w3 = pu[3];
      o0.x = bf2f(w0) * iv_pw;        o0.y = bf2f(w0 >> 16) * iv_pw;
      o0.z = bf2f(w1) * iv_pw;        o0.w = bf2f(w1 >> 16) * iv_pw;
      o1.x = bf2f(w2) * iv_pw;        o1.y = bf2f(w2 >> 16) * iv_pw;
      o1.z = bf2f(w3) * iv_pw;        o1.w = bf2f(w3 >> 16) * iv_pw;
      *(float4*)(Pdst + (size_t)it * 64) = o0;
      *(float4*)(Pdst + (size_t)it * 64 + 4) = o1;
    }
    __builtin_amdgcn_s_barrier();
  }

#pragma unroll
  for (int mi = 0; mi < 8; ++mi) {
    int row_ = base_m + wm * 128 + mi * 16 + seg * 4;
#pragma unroll
    for (int j = 0; j < 4; ++j) {
      float iv = inv[row_ + j];
#pragma unroll
      for (int ni = 0; ni < 4; ++ni)
        O[(size_t)(row_ + j) * 1024 + base_n + wn * 64 + ni * 16 + fr] =
            acc[mi][ni][j] * iv;
    }
  }
#undef LDA_H
#undef LDB_H
#undef QUADM
}

// ================= fallback fp32 path (tiny-ws safety net) =================
__global__ __launch_bounds__(256) void k_logits_raw(const float* __restrict__ Q,
                                                    const float* __restrict__ Kk,
                                                    float* __restrict__ L) {
  __shared__ float Qt[64][68];
  __shared__ float Kt[64][68];
  const int t = threadIdx.x;
  const int bm = blockIdx.x, bn = blockIdx.y;
  const float4* Q4 = (const float4*)(Q + ((size_t)bm << 12));
  const float4* K4 = (const float4*)(Kk + ((size_t)bn << 12));
#pragma unroll
  for (int i = 0; i < 4; ++i) {
    int idx = t + (i << 8);
    int r = idx >> 4;
    int k0 = (idx & 15) << 2;
    float4 a = Q4[idx];
    Qt[k0 + 0][r] = a.x; Qt[k0 + 1][r] = a.y;
    Qt[k0 + 2][r] = a.z; Qt[k0 + 3][r] = a.w;
    float4 b = K4[idx];
    Kt[k0 + 0][r] = b.x; Kt[k0 + 1][r] = b.y;
    Kt[k0 + 2][r] = b.z; Kt[k0 + 3][r] = b.w;
  }
  __syncthreads();
  const int r0 = (t >> 4) << 2;
  const int c0 = (t & 15) << 2;
  float acc[4][4] = {};
#pragma unroll 8
  for (int k = 0; k < 64; ++k) {
    float a[4], b[4];
    *(float4*)a = *(const float4*)&Qt[k][r0];
    *(float4*)b = *(const float4*)&Kt[k][c0];
#pragma unroll
    for (int i = 0; i < 4; ++i)
#pragma unroll
      for (int j = 0; j < 4; ++j)
        acc[i][j] = fmaf(a[i], b[j], acc[i][j]);
  }
  const int gr = (bm << 6) + r0;
  const int gc = (bn << 6) + c0;
#pragma unroll
  for (int i = 0; i < 4; ++i) {
    uint32_t mb = (uint32_t)(gr + i) * 4096u + (uint32_t)gc;
    float4 o;
    o.x = acc[i][0] * 0.125f + gumbel_noise(mb + 0u);
    o.y = acc[i][1] * 0.125f + gumbel_noise(mb + 1u);
    o.z = acc[i][2] * 0.125f + gumbel_noise(mb + 2u);
    o.w = acc[i][3] * 0.125f + gumbel_noise(mb + 3u);
    *(float4*)&L[(size_t)(gr + i) * 4096 + gc] = o;
  }
}

__global__ __launch_bounds__(256) void k_softmax(float* __restrict__ P) {
  const int row = blockIdx.x;
  float* Lr = P + ((size_t)row << 12);
  const int t = threadIdx.x;
  float4 v[4];
#pragma unroll
  for (int i = 0; i < 4; ++i) v[i] = ((const float4*)Lr)[t + (i << 8)];
  float mx = -3.402823466e38f;
#pragma unroll
  for (int i = 0; i < 4; ++i)
    mx = fmaxf(mx, fmaxf(fmaxf(v[i].x, v[i].y), fmaxf(v[i].z, v[i].w)));
#pragma unroll
  for (int o = 1; o < 64; o <<= 1) mx = fmaxf(mx, __shfl_xor(mx, o, 64));
  __shared__ float redm[4];
  __shared__ float reds[4];
  const int lane = t & 63, w = t >> 6;
  if (lane == 0) redm[w] = mx;
  __syncthreads();
  mx = fmaxf(fmaxf(redm[0], redm[1]), fmaxf(redm[2], redm[3]));
  float s = 0.f;
#pragma unroll
  for (int i = 0; i < 4; ++i) {
    v[i].x = expf(v[i].x - mx); v[i].y = expf(v[i].y - mx);
    v[i].z = expf(v[i].z - mx); v[i].w = expf(v[i].w - mx);
    s += (v[i].x + v[i].y) + (v[i].z + v[i].w);
  }
#pragma unroll
  for (int o = 1; o < 64; o <<= 1) s += __shfl_xor(s, o, 64);
  if (lane == 0) reds[w] = s;
  __syncthreads();
  const float inv = 1.0f / (((reds[0] + reds[1]) + (reds[2] + reds[3])));
#pragma unroll
  for (int i = 0; i < 4; ++i) {
    v[i].x *= inv; v[i].y *= inv; v[i].z *= inv; v[i].w *= inv;
    ((float4*)Lr)[t + (i << 8)] = v[i];
  }
}

__global__ __launch_bounds__(256) void k_pv(const float* __restrict__ P,
                                            const float* __restrict__ V,
                                            float* __restrict__ O) {
  __shared__ float Pt[32][132];
  __shared__ float Vs[32][132];
  const int t = threadIdx.x;
  const int base_m = blockIdx.x << 7;
  const int base_n = blockIdx.y << 7;
  const int tr = (t >> 4) << 2;
  const int tc = (t & 15) << 2;
  float acc[2][2][4][4] = {};
  for (int k0 = 0; k0 < N_LATENT; k0 += 32) {
#pragma unroll
    for (int i = 0; i < 4; ++i) {
      int idx = t + (i << 8);
      int m = idx >> 3;
      int kk = (idx & 7) << 2;
      float4 a = *(const float4*)&P[(size_t)(base_m + m) * 4096 + (k0 + kk)];
      Pt[kk + 0][m] = a.x; Pt[kk + 1][m] = a.y;
      Pt[kk + 2][m] = a.z; Pt[kk + 3][m] = a.w;
      int kv = idx >> 5;
      int n4 = (idx & 31) << 2;
      *(float4*)&Vs[kv][n4] =
          *(const float4*)&V[(size_t)(k0 + kv) * 1024 + base_n + n4];
    }
    __syncthreads();
#pragma unroll 4
    for (int k = 0; k < 32; ++k) {
      float a[2][4], b[2][4];
      *(float4*)a[0] = *(const float4*)&Pt[k][tr];
      *(float4*)a[1] = *(const float4*)&Pt[k][tr + 64];
      *(float4*)b[0] = *(const float4*)&Vs[k][tc];
      *(float4*)b[1] = *(const float4*)&Vs[k][tc + 64];
#pragma unroll
      for (int ih = 0; ih < 2; ++ih)
#pragma unroll
        for (int jh = 0; jh < 2; ++jh)
#pragma unroll
          for (int i = 0; i < 4; ++i)
#pragma unroll
            for (int j = 0; j < 4; ++j)
              acc[ih][jh][i][j] =
                  fmaf(a[ih][i], b[jh][j], acc[ih][jh][i][j]);
    }
    __syncthreads();
  }
#pragma unroll
  for (int ih = 0; ih < 2; ++ih)
#pragma unroll
    for (int i = 0; i < 4; ++i) {
      int row = base_m + (ih << 6) + tr + i;
#pragma unroll
      for (int jh = 0; jh < 2; ++jh) {
        float4 o;
        o.x = acc[ih][jh][i][0]; o.y = acc[ih][jh][i][1];
        o.z = acc[ih][jh][i][2]; o.w = acc[ih][jh][i][3];
        *(float4*)&O[(size_t)row * 1024 + base_n + (jh << 6) + tc] = o;
      }
    }
}

extern "C" void kernel_launch(void* const* d_in, const int* in_sizes, int n_in,
                              void* d_out, int out_size, void* d_ws, size_t ws_size,
                              hipStream_t stream) {
  const float* Q = (const float*)d_in[0];
  const float* K = (const float*)d_in[1];
  const float* V = (const float*)d_in[2];
  float* O = (float*)d_out;                      // [16384 x 1024]
  float* P = O + (size_t)N_GENES * N_CELLS;      // [16384 x 4096] fp32 p_attn

  const size_t pe_bytes = (size_t)N_GENES * N_LATENT * 2;   // 134.2 MB
  const size_t vt_bytes = (size_t)N_CELLS * N_LATENT * 2;   // 8.4 MB
  const size_t inv_bytes = (size_t)N_GENES * 4;             // 64 KB
  const bool fast = ws_size >= pe_bytes + vt_bytes + inv_bytes;

  if (fast) {
    ushort* Pe = (ushort*)d_ws;
    ushort* VT = (ushort*)((char*)d_ws + pe_bytes);
    float* inv = (float*)((char*)d_ws + pe_bytes + vt_bytes);
    float* Sp = P;  // 16384x64 fp32 scratch in P-region; overwritten by k_pv5

    k_logexp<<<dim3(N_GENES / 64, N_LATENT / 64), 256, 0, stream>>>(Q, K, Pe, Sp);
    k_rowinv<<<N_GENES / 256, 256, 0, stream>>>(Sp, inv);
    k_vt<<<dim3(N_LATENT / 64, N_CELLS / 64), 256, 0, stream>>>(V, VT);
    k_pv5<<<256, 512, 0, stream>>>(Pe, VT, inv, P, O);
  } else {
    k_logits_raw<<<dim3(N_GENES / 64, N_LATENT / 64), 256, 0, stream>>>(Q, K, P);
    k_softmax<<<N_GENES, 256, 0, stream>>>(P);
    k_pv<<<dim3(N_GENES / 128, N_CELLS / 128), 256, 0, stream>>>(P, V, O);
  }
}